// Round 1
// baseline (956.091 us; speedup 1.0000x reference)
//
#include <hip/hip_runtime.h>
#include <hip/hip_bf16.h>
#include <math.h>

#define T_TOK 8192
#define C_DIM 512
#define I_DIM 2048
#define E_NUM 16

#define BT 128
#define ISPLIT 4
#define IRANGE (I_DIM / ISPLIT) /* 512 */
#define BI 32
#define NCHUNK (IRANGE / BI) /* 16 */

// ws layout (bytes)
#define WS_COUNTS 0
#define WS_THR 64
#define WS_INVS 192
#define WS_RW 320
#define WS_LISTS (WS_RW + T_TOK * E_NUM * 4)  /* 524608 */
#define WS_XB (WS_LISTS + T_TOK * E_NUM * 4)  /* 1048896 */

// out offsets (float elements)
#define OUT_FULL 4194304ull
#define OUT_LOGITS 71303168ull
#define OUT_MASK 71434240ull

typedef __attribute__((ext_vector_type(8))) short bf16x8;
typedef __attribute__((ext_vector_type(4))) float f32x4;

__device__ inline unsigned short f2bf(float f) {
  unsigned u = __float_as_uint(f);
  unsigned r = u + 0x7fffu + ((u >> 16) & 1u);
  return (unsigned short)(r >> 16);
}

__device__ inline float gelu_f(float x) {
  return 0.5f * x * (1.0f + erff(x * 0.7071067811865476f));
}

__global__ void prep_kernel(const float* __restrict__ sim, const float* __restrict__ gates,
                            char* __restrict__ wsb) {
  int e = threadIdx.x;
  if (e < E_NUM) {
    ((int*)(wsb + WS_COUNTS))[e] = 0;
    double gv = (double)gates[e];
    ((double*)(wsb + WS_THR))[e] = 1.0 / (1.0 + exp(-gv));
    double ss = 0.0;
    for (int c = 0; c < C_DIM; ++c) {
      double v = (double)sim[c * E_NUM + e];
      ss += v * v;
    }
    double n = sqrt(ss);
    n = fmax(n, 1e-12);
    ((double*)(wsb + WS_INVS))[e] = 1.0 / n;
  }
}

__global__ void router_kernel(const float* __restrict__ x, const float* __restrict__ sim,
                              char* __restrict__ wsb, float* __restrict__ out) {
  const int lane = threadIdx.x & 63;
  const int t = blockIdx.x * 4 + (threadIdx.x >> 6);

  const float4* xr = (const float4*)(x + (size_t)t * C_DIM + lane * 8);
  float4 v0 = xr[0], v1 = xr[1];
  float xv[8] = {v0.x, v0.y, v0.z, v0.w, v1.x, v1.y, v1.z, v1.w};

  // bf16 copy of x for the MFMA GEMM
  unsigned p[4];
#pragma unroll
  for (int j = 0; j < 4; ++j)
    p[j] = (unsigned)f2bf(xv[2 * j]) | ((unsigned)f2bf(xv[2 * j + 1]) << 16);
  uint4 pk = {p[0], p[1], p[2], p[3]};
  *(uint4*)((unsigned short*)(wsb + WS_XB) + (size_t)t * C_DIM + lane * 8) = pk;

  double ss = 0.0;
  double acc[E_NUM];
#pragma unroll
  for (int e = 0; e < E_NUM; ++e) acc[e] = 0.0;

#pragma unroll
  for (int j = 0; j < 8; ++j) {
    const int c = lane * 8 + j;
    const double xd = (double)xv[j];
    ss += xd * xd;
    const float4* sr = (const float4*)(sim + c * E_NUM);
    float4 s0 = sr[0], s1 = sr[1], s2 = sr[2], s3 = sr[3];
    acc[0] += xd * (double)s0.x;   acc[1] += xd * (double)s0.y;
    acc[2] += xd * (double)s0.z;   acc[3] += xd * (double)s0.w;
    acc[4] += xd * (double)s1.x;   acc[5] += xd * (double)s1.y;
    acc[6] += xd * (double)s1.z;   acc[7] += xd * (double)s1.w;
    acc[8] += xd * (double)s2.x;   acc[9] += xd * (double)s2.y;
    acc[10] += xd * (double)s2.z;  acc[11] += xd * (double)s2.w;
    acc[12] += xd * (double)s3.x;  acc[13] += xd * (double)s3.y;
    acc[14] += xd * (double)s3.z;  acc[15] += xd * (double)s3.w;
  }

#define BRED(v)                 \
  v += __shfl_xor(v, 32);       \
  v += __shfl_xor(v, 16);       \
  v += __shfl_xor(v, 8);        \
  v += __shfl_xor(v, 4);        \
  v += __shfl_xor(v, 2);        \
  v += __shfl_xor(v, 1);

  BRED(ss)
#pragma unroll
  for (int e = 0; e < E_NUM; ++e) { BRED(acc[e]) }

  const double invx = 1.0 / fmax(sqrt(ss), 1e-12);
  const double* thr = (const double*)(wsb + WS_THR);
  const double* invs = (const double*)(wsb + WS_INVS);

  double lg[E_NUM], gt[E_NUM];
  bool mk[E_NUM];
  bool any = false;
#pragma unroll
  for (int e = 0; e < E_NUM; ++e) {
    lg[e] = acc[e] * invx * invs[e];
    double d = lg[e] - thr[e];
    gt[e] = d > 0.0 ? d : 0.0;
    mk[e] = d > 0.0;
    any = any || mk[e];
  }
  if (!any) {  // fallback: one-hot argmax (first max, like np.argmax)
    int be = 0;
    double bv = lg[0];
#pragma unroll
    for (int e = 1; e < E_NUM; ++e) {
      if (lg[e] > bv) { bv = lg[e]; be = e; }
    }
#pragma unroll
    for (int e = 0; e < E_NUM; ++e) mk[e] = (e == be);
  }
  double mx = -1e30;
#pragma unroll
  for (int e = 0; e < E_NUM; ++e) {
    double v = mk[e] ? gt[e] : -1e9;
    if (v > mx) mx = v;
  }
  double sum = 0.0;
  double ex[E_NUM];
#pragma unroll
  for (int e = 0; e < E_NUM; ++e) {
    ex[e] = mk[e] ? exp(gt[e] - mx) : 0.0;  // exp(-1e9-mx) underflows to 0 identically
    sum += ex[e];
  }
  const double isum = 1.0 / sum;

  if (lane == 0) {
    float* lg_out = out + OUT_LOGITS + (size_t)t * E_NUM;
    float* mk_out = out + OUT_MASK + (size_t)t * E_NUM;
    float* rw = (float*)(wsb + WS_RW) + (size_t)t * E_NUM;
    int* counts = (int*)(wsb + WS_COUNTS);
    int* lists = (int*)(wsb + WS_LISTS);
#pragma unroll
    for (int e = 0; e < E_NUM; ++e) {
      lg_out[e] = (float)lg[e];
      mk_out[e] = mk[e] ? 1.0f : 0.0f;
      rw[e] = (float)(ex[e] * isum);
      if (mk[e]) {
        int pos = atomicAdd(&counts[e], 1);
        lists[e * T_TOK + pos] = t;
      }
    }
  }
}

// Grouped expert GEMM: block = (expert e, token tile of BT, I-range of IRANGE)
// O[BT,C] += gelu(X[BT,C] @ W1[C,IRANGE]) @ W2[IRANGE,C], atomically added into full.
__global__ __launch_bounds__(512, 2) void gemm_kernel(
    const float* __restrict__ w1, const float* __restrict__ w2,
    const char* __restrict__ wsb, float* __restrict__ full) {
  const int e = blockIdx.x;
  const int ne = ((const int*)(wsb + WS_COUNTS))[e];
  const int m0 = blockIdx.y * BT;
  if (m0 >= ne) return;
  const int mcnt = min(BT, ne - m0);
  const int i0 = blockIdx.z * IRANGE;

  const int* lists = (const int*)(wsb + WS_LISTS);
  const unsigned short* xb = (const unsigned short*)(wsb + WS_XB);

  __shared__ int tl[BT];
  __shared__ unsigned short s_w1[2][C_DIM][18];  // [nt][k][n+pad2] bf16
  __shared__ unsigned short s_h[BT][40];         // [m][k+pad8] bf16

  const int tid = threadIdx.x;
  if (tid < BT) tl[tid] = lists[e * T_TOK + min(m0 + tid, ne - 1)];

  const int wv = tid >> 6;
  const int lane = tid & 63;
  const int g = lane >> 4;
  const int l15 = lane & 15;
  const int nt1 = wv & 1;  // stage-1: wave -> (nt, mgroup)
  const int mg = wv >> 1;

  const f32x4 zero4 = {0.f, 0.f, 0.f, 0.f};
  f32x4 acc[8][4];
#pragma unroll
  for (int m = 0; m < 8; ++m)
#pragma unroll
    for (int n = 0; n < 4; ++n) acc[m][n] = zero4;

  const float* w1p = w1 + (size_t)e * C_DIM * I_DIM + i0;
  const float* w2p = w2 + (size_t)e * I_DIM * C_DIM + (size_t)i0 * C_DIM;

  for (int ci = 0; ci < NCHUNK; ++ci) {
    // stage W1 chunk [512][32] f32 -> bf16 LDS (coalesced float4 reads)
#pragma unroll
    for (int it = 0; it < 8; ++it) {
      const int q = tid + it * 512;
      const int k = q >> 3;
      const int n4 = (q & 7) * 4;
      const float4 v = *(const float4*)(w1p + (size_t)k * I_DIM + ci * BI + n4);
      const int nt = n4 >> 4, nn = n4 & 15;
      s_w1[nt][k][nn + 0] = f2bf(v.x);
      s_w1[nt][k][nn + 1] = f2bf(v.y);
      s_w1[nt][k][nn + 2] = f2bf(v.z);
      s_w1[nt][k][nn + 3] = f2bf(v.w);
    }
    __syncthreads();

    // stage 1: H[128][32] = X @ W1c, fused exact GELU, -> s_h
    {
      f32x4 hacc[2];
      hacc[0] = zero4;
      hacc[1] = zero4;
      for (int kk = 0; kk < 16; ++kk) {
        const int k0 = kk * 32;
        bf16x8 b;
#pragma unroll
        for (int j = 0; j < 8; ++j) b[j] = (short)s_w1[nt1][k0 + g * 8 + j][l15];
#pragma unroll
        for (int mf = 0; mf < 2; ++mf) {
          const int row = mg * 32 + mf * 16 + l15;
          const int t = tl[row];
          union { uint4 u; bf16x8 v; } av;
          av.u = *(const uint4*)(xb + (size_t)t * C_DIM + k0 + g * 8);
          hacc[mf] = __builtin_amdgcn_mfma_f32_16x16x32_bf16(av.v, b, hacc[mf], 0, 0, 0);
        }
      }
#pragma unroll
      for (int mf = 0; mf < 2; ++mf) {
        const int rbase = mg * 32 + mf * 16 + g * 4;
        const int col = nt1 * 16 + l15;
#pragma unroll
        for (int r = 0; r < 4; ++r) s_h[rbase + r][col] = f2bf(gelu_f(hacc[mf][r]));
      }
    }
    __syncthreads();

    // stage 2: acc += H @ W2c  (wave owns C-columns [wv*64, wv*64+64))
    {
      bf16x8 a2[8];
#pragma unroll
      for (int m = 0; m < 8; ++m) {
        union { uint4 u; bf16x8 v; } av;
        av.u = *(const uint4*)(&s_h[m * 16 + l15][g * 8]);
        a2[m] = av.v;
      }
#pragma unroll
      for (int nt = 0; nt < 4; ++nt) {
        const int c = wv * 64 + nt * 16 + l15;
        bf16x8 b;
#pragma unroll
        for (int j = 0; j < 8; ++j) {
          const int ki = ci * BI + g * 8 + j;
          b[j] = (short)f2bf(w2p[(size_t)ki * C_DIM + c]);
        }
#pragma unroll
        for (int m = 0; m < 8; ++m)
          acc[m][nt] = __builtin_amdgcn_mfma_f32_16x16x32_bf16(a2[m], b, acc[m][nt], 0, 0, 0);
      }
    }
    __syncthreads();  // protects s_h: next chunk's stage-1 writes it after this point
  }

  // epilogue: atomic add partials into full_expert_outputs
#pragma unroll
  for (int m = 0; m < 8; ++m) {
#pragma unroll
    for (int r = 0; r < 4; ++r) {
      const int row = m * 16 + g * 4 + r;
      if (row < mcnt) {
        const int t = tl[row];
        float* dst = full + ((size_t)t * E_NUM + e) * C_DIM + wv * 64 + l15;
#pragma unroll
        for (int nt = 0; nt < 4; ++nt) atomicAdd(dst + nt * 16, acc[m][nt][r]);
      }
    }
  }
}

__global__ void finalize_kernel(const float* __restrict__ full, const char* __restrict__ wsb,
                                float* __restrict__ fin) {
  const int t = blockIdx.x;
  const int tid = threadIdx.x;
  const float* rw = (const float*)(wsb + WS_RW);
  __shared__ float rws[E_NUM];
  if (tid < E_NUM) rws[tid] = rw[t * E_NUM + tid];
  __syncthreads();
  float a0 = 0.f, a1 = 0.f;
  const float* base = full + (size_t)t * E_NUM * C_DIM;
#pragma unroll 1
  for (int e = 0; e < E_NUM; ++e) {
    const float w = rws[e];
    if (w != 0.0f) {
      a0 += w * base[e * C_DIM + tid];
      a1 += w * base[e * C_DIM + 256 + tid];
    }
  }
  fin[(size_t)t * C_DIM + tid] = a0;
  fin[(size_t)t * C_DIM + 256 + tid] = a1;
}

extern "C" void kernel_launch(void* const* d_in, const int* in_sizes, int n_in,
                              void* d_out, int out_size, void* d_ws, size_t ws_size,
                              hipStream_t stream) {
  const float* x = (const float*)d_in[0];
  const float* sim = (const float*)d_in[1];
  const float* gates = (const float*)d_in[2];
  const float* w1 = (const float*)d_in[3];
  const float* w2 = (const float*)d_in[4];
  float* out = (float*)d_out;
  char* wsb = (char*)d_ws;

  hipMemsetAsync(d_out, 0, (size_t)out_size * sizeof(float), stream);
  hipLaunchKernelGGL(prep_kernel, dim3(1), dim3(64), 0, stream, sim, gates, wsb);
  hipLaunchKernelGGL(router_kernel, dim3(T_TOK / 4), dim3(256), 0, stream, x, sim, wsb, out);
  hipLaunchKernelGGL(gemm_kernel, dim3(E_NUM, T_TOK / BT, ISPLIT), dim3(512), 0, stream,
                     w1, w2, wsb, out + OUT_FULL);
  hipLaunchKernelGGL(finalize_kernel, dim3(T_TOK), dim3(256), 0, stream, out + OUT_FULL, wsb, out);
}

// Round 2
// 832.147 us; speedup vs baseline: 1.1489x; 1.1489x over previous
//
#include <hip/hip_runtime.h>
#include <hip/hip_bf16.h>
#include <math.h>

#define T_TOK 8192
#define C_DIM 512
#define I_DIM 2048
#define E_NUM 16

#define BT 128
#define ISPLIT 8
#define IRANGE (I_DIM / ISPLIT) /* 256 */
#define BI 32
#define NCHUNK (IRANGE / BI) /* 8 */
#define CAP 1024
#define NTILE (CAP / BT) /* 8 */

// ws layout (bytes). Fallback path uses only up to WS_XB end (~9.44MB, proven to fit).
#define WS_COUNTS 0
#define WS_THR 64
#define WS_INVS 128
#define WS_RW 192
#define WS_LISTS 524480
#define WS_XB 1048768
#define WS_POS 9437376
#define WS_COMPACT 10485760ull
#define WS_W1T 44040192ull
#define WS_W2T 77594624ull
#define WS_NEED_FAST 111149056ull

// out offsets (float elements)
#define OUT_FULL 4194304ull
#define OUT_LOGITS 71303168ull
#define OUT_MASK 71434240ull

typedef __attribute__((ext_vector_type(8))) short bf16x8;
typedef __attribute__((ext_vector_type(4))) float f32x4;

__device__ inline unsigned short f2bf(float f) {
  unsigned u = __float_as_uint(f);
  unsigned r = u + 0x7fffu + ((u >> 16) & 1u);
  return (unsigned short)(r >> 16);
}

__device__ inline bf16x8 ldb8(const unsigned short* p) {
  union { uint4 u; bf16x8 v; } w;
  w.u = *(const uint4*)p;
  return w.v;
}

__device__ inline float gelu_f(float x) {
  return 0.5f * x * (1.0f + erff(x * 0.7071067811865476f));
}

__global__ void prep_kernel(const float* __restrict__ sim, const float* __restrict__ gates,
                            char* __restrict__ wsb) {
  int e = threadIdx.x;
  if (e < E_NUM) {
    ((int*)(wsb + WS_COUNTS))[e] = 0;
    ((float*)(wsb + WS_THR))[e] = 1.0f / (1.0f + expf(-gates[e]));
    float ss = 0.0f;
    for (int c = 0; c < C_DIM; ++c) {
      float v = sim[c * E_NUM + e];
      ss += v * v;
    }
    float n = fmaxf(sqrtf(ss), 1e-12f);
    ((float*)(wsb + WS_INVS))[e] = 1.0f / n;
  }
}

__global__ void router_kernel(const float* __restrict__ x, const float* __restrict__ sim,
                              char* __restrict__ wsb, float* __restrict__ out, int fast) {
  const int lane = threadIdx.x & 63;
  const int t = blockIdx.x * 4 + (threadIdx.x >> 6);

  const float4* xr = (const float4*)(x + (size_t)t * C_DIM + lane * 8);
  float4 v0 = xr[0], v1 = xr[1];
  float xv[8] = {v0.x, v0.y, v0.z, v0.w, v1.x, v1.y, v1.z, v1.w};

  // bf16 copy of x for the MFMA GEMM
  unsigned p[4];
#pragma unroll
  for (int j = 0; j < 4; ++j)
    p[j] = (unsigned)f2bf(xv[2 * j]) | ((unsigned)f2bf(xv[2 * j + 1]) << 16);
  uint4 pk = {p[0], p[1], p[2], p[3]};
  *(uint4*)((unsigned short*)(wsb + WS_XB) + (size_t)t * C_DIM + lane * 8) = pk;

  float ss = 0.0f;
  float acc[E_NUM];
#pragma unroll
  for (int e = 0; e < E_NUM; ++e) acc[e] = 0.0f;

#pragma unroll
  for (int j = 0; j < 8; ++j) {
    const int c = lane * 8 + j;
    const float xd = xv[j];
    ss += xd * xd;
    const float4* sr = (const float4*)(sim + c * E_NUM);
    float4 s0 = sr[0], s1 = sr[1], s2 = sr[2], s3 = sr[3];
    acc[0] += xd * s0.x;   acc[1] += xd * s0.y;
    acc[2] += xd * s0.z;   acc[3] += xd * s0.w;
    acc[4] += xd * s1.x;   acc[5] += xd * s1.y;
    acc[6] += xd * s1.z;   acc[7] += xd * s1.w;
    acc[8] += xd * s2.x;   acc[9] += xd * s2.y;
    acc[10] += xd * s2.z;  acc[11] += xd * s2.w;
    acc[12] += xd * s3.x;  acc[13] += xd * s3.y;
    acc[14] += xd * s3.z;  acc[15] += xd * s3.w;
  }

#define BRED(v)                 \
  v += __shfl_xor(v, 32);       \
  v += __shfl_xor(v, 16);       \
  v += __shfl_xor(v, 8);        \
  v += __shfl_xor(v, 4);        \
  v += __shfl_xor(v, 2);        \
  v += __shfl_xor(v, 1);

  BRED(ss)
#pragma unroll
  for (int e = 0; e < E_NUM; ++e) { BRED(acc[e]) }

  const float invx = 1.0f / fmaxf(sqrtf(ss), 1e-12f);
  const float* thr = (const float*)(wsb + WS_THR);
  const float* invs = (const float*)(wsb + WS_INVS);

  float lg[E_NUM], gt[E_NUM];
  bool mk[E_NUM];
  bool any = false;
#pragma unroll
  for (int e = 0; e < E_NUM; ++e) {
    lg[e] = acc[e] * invx * invs[e];
    float d = lg[e] - thr[e];
    gt[e] = d > 0.0f ? d : 0.0f;
    mk[e] = d > 0.0f;
    any = any || mk[e];
  }
  if (!any) {  // fallback: one-hot argmax (first max, like np.argmax)
    int be = 0;
    float bv = lg[0];
#pragma unroll
    for (int e = 1; e < E_NUM; ++e) {
      if (lg[e] > bv) { bv = lg[e]; be = e; }
    }
#pragma unroll
    for (int e = 0; e < E_NUM; ++e) mk[e] = (e == be);
  }
  float mx = -1e30f;
#pragma unroll
  for (int e = 0; e < E_NUM; ++e) {
    float v = mk[e] ? gt[e] : -1e9f;
    if (v > mx) mx = v;
  }
  float sum = 0.0f;
  float ex[E_NUM];
#pragma unroll
  for (int e = 0; e < E_NUM; ++e) {
    ex[e] = mk[e] ? expf(gt[e] - mx) : 0.0f;
    sum += ex[e];
  }
  const float isum = 1.0f / sum;

  if (lane == 0) {
    float* lg_out = out + OUT_LOGITS + (size_t)t * E_NUM;
    float* mk_out = out + OUT_MASK + (size_t)t * E_NUM;
    float* rw = (float*)(wsb + WS_RW) + (size_t)t * E_NUM;
    int* counts = (int*)(wsb + WS_COUNTS);
    int* lists = (int*)(wsb + WS_LISTS);
    int* posm = (int*)(wsb + WS_POS);
#pragma unroll
    for (int e = 0; e < E_NUM; ++e) {
      lg_out[e] = lg[e];
      mk_out[e] = mk[e] ? 1.0f : 0.0f;
      rw[e] = ex[e] * isum;
      int pos = -1;
      if (mk[e]) {
        pos = atomicAdd(&counts[e], 1);
        lists[e * T_TOK + pos] = t;
      }
      if (fast) posm[t * E_NUM + e] = pos;
    }
  }
}

// Tiled transpose+convert: src f32 [E][R][Cin] -> dst bf16 [E][Cin][R]
__global__ void transpose_kernel(const float* __restrict__ src, unsigned short* __restrict__ dst,
                                 int R, int Cin) {
  const int e = blockIdx.z;
  const int rt = blockIdx.y * 64, ct = blockIdx.x * 64;
  const float* se = src + (size_t)e * R * Cin;
  unsigned short* de = dst + (size_t)e * R * Cin;
  __shared__ unsigned short tile[64][68];
  const int tid = threadIdx.x;
  const int tr = tid >> 4, tc = (tid & 15) * 4;
#pragma unroll
  for (int it = 0; it < 4; ++it) {
    const int r = tr + it * 16;
    const float4 v = *(const float4*)(se + (size_t)(rt + r) * Cin + ct + tc);
    tile[tc + 0][r] = f2bf(v.x);
    tile[tc + 1][r] = f2bf(v.y);
    tile[tc + 2][r] = f2bf(v.z);
    tile[tc + 3][r] = f2bf(v.w);
  }
  __syncthreads();
#pragma unroll
  for (int it = 0; it < 4; ++it) {
    const int c = tr + it * 16;
    ushort4 o = *(const ushort4*)&tile[c][tc];
    *(ushort4*)(de + (size_t)(ct + c) * R + rt + tc) = o;
  }
}

// Fast grouped expert GEMM: weights pre-transposed bf16 in ws, no weight staging.
// Output: atomicAdd partials into compact[e][pos][c].
__global__ __launch_bounds__(512) void gemm_fast_kernel(const char* __restrict__ wsb,
                                                        float* __restrict__ compact) {
  const int e = blockIdx.x;
  const int ne = min(((const int*)(wsb + WS_COUNTS))[e], CAP);
  const int m0 = blockIdx.y * BT;
  if (m0 >= ne) return;
  const int mcnt = min(BT, ne - m0);
  const int i0 = blockIdx.z * IRANGE;

  const int* lists = (const int*)(wsb + WS_LISTS);
  const unsigned short* xb = (const unsigned short*)(wsb + WS_XB);
  const unsigned short* w1t = (const unsigned short*)(wsb + WS_W1T) + (size_t)e * I_DIM * C_DIM;
  const unsigned short* w2t = (const unsigned short*)(wsb + WS_W2T) + (size_t)e * C_DIM * I_DIM;

  __shared__ int tl[BT];
  __shared__ unsigned short s_h[BT][BI + 8];

  const int tid = threadIdx.x;
  if (tid < BT) tl[tid] = lists[e * T_TOK + min(m0 + tid, ne - 1)];
  __syncthreads();

  const int wv = tid >> 6, lane = tid & 63, g = lane >> 4, l15 = lane & 15;
  const int nt1 = wv & 1, mg = wv >> 1;

  const f32x4 zero4 = {0.f, 0.f, 0.f, 0.f};
  f32x4 acc[8][4];
#pragma unroll
  for (int m = 0; m < 8; ++m)
#pragma unroll
    for (int n = 0; n < 4; ++n) acc[m][n] = zero4;

  // stage-1 A rows are fixed across chunks
  const unsigned short* a0p = xb + (size_t)tl[mg * 32 + l15] * C_DIM;
  const unsigned short* a1p = xb + (size_t)tl[mg * 32 + 16 + l15] * C_DIM;

  for (int ci = 0; ci < NCHUNK; ++ci) {
    const int ib = i0 + ci * BI;
    // stage 1: H[128][32] = X @ W1c (B-rows direct from W1T global)
    f32x4 h0 = zero4, h1 = zero4;
    const unsigned short* brow = w1t + (size_t)(ib + nt1 * 16 + l15) * C_DIM;
#pragma unroll
    for (int kk = 0; kk < 16; ++kk) {
      const int k0 = kk * 32 + g * 8;
      const bf16x8 b = ldb8(brow + k0);
      h0 = __builtin_amdgcn_mfma_f32_16x16x32_bf16(ldb8(a0p + k0), b, h0, 0, 0, 0);
      h1 = __builtin_amdgcn_mfma_f32_16x16x32_bf16(ldb8(a1p + k0), b, h1, 0, 0, 0);
    }
    __syncthreads();  // previous chunk's stage-2 reads of s_h complete
    {
      const int col = nt1 * 16 + l15;
      const int rb = mg * 32 + g * 4;
#pragma unroll
      for (int r = 0; r < 4; ++r) {
        s_h[rb + r][col] = f2bf(gelu_f(h0[r]));
        s_h[rb + 16 + r][col] = f2bf(gelu_f(h1[r]));
      }
    }
    __syncthreads();
    // stage 2: acc += H @ W2c (wave owns C-columns [wv*64, wv*64+64))
    bf16x8 b2[4];
#pragma unroll
    for (int nt = 0; nt < 4; ++nt)
      b2[nt] = ldb8(w2t + (size_t)(wv * 64 + nt * 16 + l15) * I_DIM + ib + g * 8);
#pragma unroll
    for (int m = 0; m < 8; ++m) {
      const bf16x8 a2 = ldb8(&s_h[m * 16 + l15][g * 8]);
#pragma unroll
      for (int nt = 0; nt < 4; ++nt)
        acc[m][nt] = __builtin_amdgcn_mfma_f32_16x16x32_bf16(a2, b2[nt], acc[m][nt], 0, 0, 0);
    }
  }

  // epilogue: atomic add partials into compact[e][pos][c]
#pragma unroll
  for (int m = 0; m < 8; ++m) {
#pragma unroll
    for (int r = 0; r < 4; ++r) {
      const int row = m * 16 + g * 4 + r;
      if (row < mcnt) {
        float* dst = compact + ((size_t)e * CAP + m0 + row) * C_DIM + wv * 64 + l15;
#pragma unroll
        for (int nt = 0; nt < 4; ++nt) atomicAdd(dst + nt * 16, acc[m][nt][r]);
      }
    }
  }
}

// One pass: write full (value or 0 everywhere) + final = sum_e rw * full
__global__ void scatter_kernel(const float* __restrict__ compact, const char* __restrict__ wsb,
                               float* __restrict__ out) {
  const int t = blockIdx.x;
  const int tid = threadIdx.x;  // 256
  __shared__ float rws[E_NUM];
  __shared__ int ps[E_NUM];
  if (tid < E_NUM) {
    rws[tid] = ((const float*)(wsb + WS_RW))[t * E_NUM + tid];
    ps[tid] = ((const int*)(wsb + WS_POS))[t * E_NUM + tid];
  }
  __syncthreads();
  float a0 = 0.f, a1 = 0.f;
  float* full = out + OUT_FULL + (size_t)t * E_NUM * C_DIM;
#pragma unroll 1
  for (int e = 0; e < E_NUM; ++e) {
    const int p = ps[e];
    float v0 = 0.f, v1 = 0.f;
    if (p >= 0 && p < CAP) {
      const float* src = compact + ((size_t)e * CAP + p) * C_DIM;
      v0 = src[tid];
      v1 = src[tid + 256];
      const float w = rws[e];
      a0 += w * v0;
      a1 += w * v1;
    }
    full[e * C_DIM + tid] = v0;
    full[e * C_DIM + tid + 256] = v1;
  }
  out[(size_t)t * C_DIM + tid] = a0;
  out[(size_t)t * C_DIM + tid + 256] = a1;
}

// ---------------- fallback path (round-1 structure), used if ws too small ----------------
__global__ __launch_bounds__(512, 2) void gemm_kernel(
    const float* __restrict__ w1, const float* __restrict__ w2,
    const char* __restrict__ wsb, float* __restrict__ full) {
  const int e = blockIdx.x;
  const int ne = ((const int*)(wsb + WS_COUNTS))[e];
  const int m0 = blockIdx.y * BT;
  if (m0 >= ne) return;
  const int mcnt = min(BT, ne - m0);
  const int i0 = blockIdx.z * IRANGE;

  const int* lists = (const int*)(wsb + WS_LISTS);
  const unsigned short* xb = (const unsigned short*)(wsb + WS_XB);

  __shared__ int tl[BT];
  __shared__ unsigned short s_w1[2][C_DIM][18];
  __shared__ unsigned short s_h[BT][40];

  const int tid = threadIdx.x;
  if (tid < BT) tl[tid] = lists[e * T_TOK + min(m0 + tid, ne - 1)];

  const int wv = tid >> 6;
  const int lane = tid & 63;
  const int g = lane >> 4;
  const int l15 = lane & 15;
  const int nt1 = wv & 1;
  const int mg = wv >> 1;

  const f32x4 zero4 = {0.f, 0.f, 0.f, 0.f};
  f32x4 acc[8][4];
#pragma unroll
  for (int m = 0; m < 8; ++m)
#pragma unroll
    for (int n = 0; n < 4; ++n) acc[m][n] = zero4;

  const float* w1p = w1 + (size_t)e * C_DIM * I_DIM + i0;
  const float* w2p = w2 + (size_t)e * I_DIM * C_DIM + (size_t)i0 * C_DIM;

  for (int ci = 0; ci < NCHUNK; ++ci) {
#pragma unroll
    for (int it = 0; it < 8; ++it) {
      const int q = tid + it * 512;
      const int k = q >> 3;
      const int n4 = (q & 7) * 4;
      const float4 v = *(const float4*)(w1p + (size_t)k * I_DIM + ci * BI + n4);
      const int nt = n4 >> 4, nn = n4 & 15;
      s_w1[nt][k][nn + 0] = f2bf(v.x);
      s_w1[nt][k][nn + 1] = f2bf(v.y);
      s_w1[nt][k][nn + 2] = f2bf(v.z);
      s_w1[nt][k][nn + 3] = f2bf(v.w);
    }
    __syncthreads();
    {
      f32x4 hacc[2];
      hacc[0] = zero4;
      hacc[1] = zero4;
      for (int kk = 0; kk < 16; ++kk) {
        const int k0 = kk * 32;
        bf16x8 b;
#pragma unroll
        for (int j = 0; j < 8; ++j) b[j] = (short)s_w1[nt1][k0 + g * 8 + j][l15];
#pragma unroll
        for (int mf = 0; mf < 2; ++mf) {
          const int row = mg * 32 + mf * 16 + l15;
          const int t = tl[row];
          union { uint4 u; bf16x8 v; } av;
          av.u = *(const uint4*)(xb + (size_t)t * C_DIM + k0 + g * 8);
          hacc[mf] = __builtin_amdgcn_mfma_f32_16x16x32_bf16(av.v, b, hacc[mf], 0, 0, 0);
        }
      }
#pragma unroll
      for (int mf = 0; mf < 2; ++mf) {
        const int rbase = mg * 32 + mf * 16 + g * 4;
        const int col = nt1 * 16 + l15;
#pragma unroll
        for (int r = 0; r < 4; ++r) s_h[rbase + r][col] = f2bf(gelu_f(hacc[mf][r]));
      }
    }
    __syncthreads();
    {
      bf16x8 a2[8];
#pragma unroll
      for (int m = 0; m < 8; ++m) {
        union { uint4 u; bf16x8 v; } av;
        av.u = *(const uint4*)(&s_h[m * 16 + l15][g * 8]);
        a2[m] = av.v;
      }
#pragma unroll
      for (int nt = 0; nt < 4; ++nt) {
        const int c = wv * 64 + nt * 16 + l15;
        bf16x8 b;
#pragma unroll
        for (int j = 0; j < 8; ++j) {
          const int ki = ci * BI + g * 8 + j;
          b[j] = (short)f2bf(w2p[(size_t)ki * C_DIM + c]);
        }
#pragma unroll
        for (int m = 0; m < 8; ++m)
          acc[m][nt] = __builtin_amdgcn_mfma_f32_16x16x32_bf16(a2[m], b, acc[m][nt], 0, 0, 0);
      }
    }
    __syncthreads();
  }

#pragma unroll
  for (int m = 0; m < 8; ++m) {
#pragma unroll
    for (int r = 0; r < 4; ++r) {
      const int row = m * 16 + g * 4 + r;
      if (row < mcnt) {
        const int t = tl[row];
        float* dst = full + ((size_t)t * E_NUM + e) * C_DIM + wv * 64 + l15;
#pragma unroll
        for (int nt = 0; nt < 4; ++nt) atomicAdd(dst + nt * 16, acc[m][nt][r]);
      }
    }
  }
}

__global__ void finalize_kernel(const float* __restrict__ full, const char* __restrict__ wsb,
                                float* __restrict__ fin) {
  const int t = blockIdx.x;
  const int tid = threadIdx.x;
  const float* rw = (const float*)(wsb + WS_RW);
  __shared__ float rws[E_NUM];
  if (tid < E_NUM) rws[tid] = rw[t * E_NUM + tid];
  __syncthreads();
  float a0 = 0.f, a1 = 0.f;
  const float* base = full + (size_t)t * E_NUM * C_DIM;
#pragma unroll 1
  for (int e = 0; e < E_NUM; ++e) {
    const float w = rws[e];
    if (w != 0.0f) {
      a0 += w * base[e * C_DIM + tid];
      a1 += w * base[e * C_DIM + 256 + tid];
    }
  }
  fin[(size_t)t * C_DIM + tid] = a0;
  fin[(size_t)t * C_DIM + 256 + tid] = a1;
}

extern "C" void kernel_launch(void* const* d_in, const int* in_sizes, int n_in,
                              void* d_out, int out_size, void* d_ws, size_t ws_size,
                              hipStream_t stream) {
  const float* x = (const float*)d_in[0];
  const float* sim = (const float*)d_in[1];
  const float* gates = (const float*)d_in[2];
  const float* w1 = (const float*)d_in[3];
  const float* w2 = (const float*)d_in[4];
  float* out = (float*)d_out;
  char* wsb = (char*)d_ws;
  const int fast = ws_size >= (size_t)WS_NEED_FAST;

  hipLaunchKernelGGL(prep_kernel, dim3(1), dim3(64), 0, stream, sim, gates, wsb);
  hipLaunchKernelGGL(router_kernel, dim3(T_TOK / 4), dim3(256), 0, stream, x, sim, wsb, out, fast);

  if (fast) {
    // W1 [E][512][2048] -> W1T [E][2048][512]; W2 [E][2048][512] -> W2T [E][512][2048]
    hipLaunchKernelGGL(transpose_kernel, dim3(I_DIM / 64, C_DIM / 64, E_NUM), dim3(256), 0, stream,
                       w1, (unsigned short*)(wsb + WS_W1T), C_DIM, I_DIM);
    hipLaunchKernelGGL(transpose_kernel, dim3(C_DIM / 64, I_DIM / 64, E_NUM), dim3(256), 0, stream,
                       w2, (unsigned short*)(wsb + WS_W2T), I_DIM, C_DIM);
    hipMemsetAsync(wsb + WS_COMPACT, 0, (size_t)E_NUM * CAP * C_DIM * 4, stream);
    hipLaunchKernelGGL(gemm_fast_kernel, dim3(E_NUM, NTILE, ISPLIT), dim3(512), 0, stream,
                       wsb, (float*)(wsb + WS_COMPACT));
    hipLaunchKernelGGL(scatter_kernel, dim3(T_TOK), dim3(256), 0, stream,
                       (const float*)(wsb + WS_COMPACT), wsb, out);
  } else {
    hipMemsetAsync(d_out, 0, (size_t)out_size * sizeof(float), stream);
    hipLaunchKernelGGL(gemm_kernel, dim3(E_NUM, T_TOK / BT, ISPLIT), dim3(512), 0, stream,
                       w1, w2, wsb, out + OUT_FULL);
    hipLaunchKernelGGL(finalize_kernel, dim3(T_TOK), dim3(256), 0, stream, out + OUT_FULL, wsb, out);
  }
}

// Round 3
// 463.006 us; speedup vs baseline: 2.0650x; 1.7973x over previous
//
#include <hip/hip_runtime.h>
#include <hip/hip_bf16.h>
#include <math.h>

#define T_TOK 8192
#define C_DIM 512
#define I_DIM 2048
#define E_NUM 16

#define BT 128
#define ISPLIT 8
#define IRANGE (I_DIM / ISPLIT) /* 256 */
#define BI 32
#define NCHUNK (IRANGE / BI) /* 8 */
#define CAP 1024
#define NTILE (CAP / BT) /* 8 */

// ws layout (bytes). Fallback path uses only up to WS_MASKB end (~10MB, proven to fit).
#define WS_COUNTS 0
#define WS_THR 64
#define WS_INVS 128
#define WS_RW 192
#define WS_LISTS 524480
#define WS_XB 1048768
#define WS_POS 9437376
#define WS_MASKB 9961664
#define WS_COMPACT 10485760ull
#define WS_W1T 44040192ull
#define WS_W2T 77594624ull
#define WS_NEED_FAST 111149056ull

// out offsets (float elements)
#define OUT_FULL 4194304ull
#define OUT_LOGITS 71303168ull
#define OUT_MASK 71434240ull

typedef __attribute__((ext_vector_type(8))) short bf16x8;
typedef __attribute__((ext_vector_type(4))) float f32x4;

__device__ inline unsigned short f2bf(float f) {
  unsigned u = __float_as_uint(f);
  unsigned r = u + 0x7fffu + ((u >> 16) & 1u);
  return (unsigned short)(r >> 16);
}

__device__ inline bf16x8 ldb8(const unsigned short* p) {
  union { uint4 u; bf16x8 v; } w;
  w.u = *(const uint4*)p;
  return w.v;
}

__device__ inline float gelu_f(float x) {
  return 0.5f * x * (1.0f + erff(x * 0.7071067811865476f));
}

__global__ void prep_kernel(const float* __restrict__ sim, const float* __restrict__ gates,
                            char* __restrict__ wsb) {
  int e = threadIdx.x;
  if (e < E_NUM) {
    ((float*)(wsb + WS_THR))[e] = 1.0f / (1.0f + expf(-gates[e]));
    float ss = 0.0f;
    for (int c = 0; c < C_DIM; ++c) {
      float v = sim[c * E_NUM + e];
      ss += v * v;
    }
    float n = fmaxf(sqrtf(ss), 1e-12f);
    ((float*)(wsb + WS_INVS))[e] = 1.0f / n;
  }
}

// Per-token routing. NO atomics: writes per-token results + 16-bit mask word only.
__global__ void router_kernel(const float* __restrict__ x, const float* __restrict__ sim,
                              char* __restrict__ wsb, float* __restrict__ out) {
  const int lane = threadIdx.x & 63;
  const int t = blockIdx.x * 4 + (threadIdx.x >> 6);

  const float4* xr = (const float4*)(x + (size_t)t * C_DIM + lane * 8);
  float4 v0 = xr[0], v1 = xr[1];
  float xv[8] = {v0.x, v0.y, v0.z, v0.w, v1.x, v1.y, v1.z, v1.w};

  // bf16 copy of x for the MFMA GEMM
  unsigned p[4];
#pragma unroll
  for (int j = 0; j < 4; ++j)
    p[j] = (unsigned)f2bf(xv[2 * j]) | ((unsigned)f2bf(xv[2 * j + 1]) << 16);
  uint4 pk = {p[0], p[1], p[2], p[3]};
  *(uint4*)((unsigned short*)(wsb + WS_XB) + (size_t)t * C_DIM + lane * 8) = pk;

  float ss = 0.0f;
  float acc[E_NUM];
#pragma unroll
  for (int e = 0; e < E_NUM; ++e) acc[e] = 0.0f;

#pragma unroll
  for (int j = 0; j < 8; ++j) {
    const int c = lane * 8 + j;
    const float xd = xv[j];
    ss += xd * xd;
    const float4* sr = (const float4*)(sim + c * E_NUM);
    float4 s0 = sr[0], s1 = sr[1], s2 = sr[2], s3 = sr[3];
    acc[0] += xd * s0.x;   acc[1] += xd * s0.y;
    acc[2] += xd * s0.z;   acc[3] += xd * s0.w;
    acc[4] += xd * s1.x;   acc[5] += xd * s1.y;
    acc[6] += xd * s1.z;   acc[7] += xd * s1.w;
    acc[8] += xd * s2.x;   acc[9] += xd * s2.y;
    acc[10] += xd * s2.z;  acc[11] += xd * s2.w;
    acc[12] += xd * s3.x;  acc[13] += xd * s3.y;
    acc[14] += xd * s3.z;  acc[15] += xd * s3.w;
  }

#define BRED(v)                 \
  v += __shfl_xor(v, 32);       \
  v += __shfl_xor(v, 16);       \
  v += __shfl_xor(v, 8);        \
  v += __shfl_xor(v, 4);        \
  v += __shfl_xor(v, 2);        \
  v += __shfl_xor(v, 1);

  BRED(ss)
#pragma unroll
  for (int e = 0; e < E_NUM; ++e) { BRED(acc[e]) }

  const float invx = 1.0f / fmaxf(sqrtf(ss), 1e-12f);
  const float* thr = (const float*)(wsb + WS_THR);
  const float* invs = (const float*)(wsb + WS_INVS);

  float lg[E_NUM], gt[E_NUM];
  bool mk[E_NUM];
  bool any = false;
#pragma unroll
  for (int e = 0; e < E_NUM; ++e) {
    lg[e] = acc[e] * invx * invs[e];
    float d = lg[e] - thr[e];
    gt[e] = d > 0.0f ? d : 0.0f;
    mk[e] = d > 0.0f;
    any = any || mk[e];
  }
  if (!any) {  // fallback: one-hot argmax (first max, like np.argmax)
    int be = 0;
    float bv = lg[0];
#pragma unroll
    for (int e = 1; e < E_NUM; ++e) {
      if (lg[e] > bv) { bv = lg[e]; be = e; }
    }
#pragma unroll
    for (int e = 0; e < E_NUM; ++e) mk[e] = (e == be);
  }
  float mx = -1e30f;
#pragma unroll
  for (int e = 0; e < E_NUM; ++e) {
    float v = mk[e] ? gt[e] : -1e9f;
    if (v > mx) mx = v;
  }
  float sum = 0.0f;
  float ex[E_NUM];
#pragma unroll
  for (int e = 0; e < E_NUM; ++e) {
    ex[e] = mk[e] ? expf(gt[e] - mx) : 0.0f;
    sum += ex[e];
  }
  const float isum = 1.0f / sum;

  if (lane == 0) {
    float* lg_out = out + OUT_LOGITS + (size_t)t * E_NUM;
    float* mk_out = out + OUT_MASK + (size_t)t * E_NUM;
    float* rw = (float*)(wsb + WS_RW) + (size_t)t * E_NUM;
    unsigned mb = 0;
#pragma unroll
    for (int e = 0; e < E_NUM; ++e) {
      lg_out[e] = lg[e];
      mk_out[e] = mk[e] ? 1.0f : 0.0f;
      rw[e] = ex[e] * isum;
      if (mk[e]) mb |= (1u << e);
    }
    ((unsigned*)(wsb + WS_MASKB))[t] = mb;
  }
}

// Deterministic list build: one block per expert, prefix-scan over 8192 mask bits.
__global__ __launch_bounds__(1024) void build_lists_kernel(char* __restrict__ wsb) {
  const int e = blockIdx.x;
  const int tid = threadIdx.x;
  const unsigned* maskb = (const unsigned*)(wsb + WS_MASKB);
  const int t0 = tid * 8;
  unsigned flags = 0;
#pragma unroll
  for (int j = 0; j < 8; ++j)
    if (maskb[t0 + j] & (1u << e)) flags |= (1u << j);
  const int cnt = __popc(flags);
  const int lane = tid & 63, wid = tid >> 6;
  int v = cnt;
#pragma unroll
  for (int off = 1; off < 64; off <<= 1) {
    int u = __shfl_up(v, off);
    if (lane >= off) v += u;
  }
  __shared__ int wsum[16];
  if (lane == 63) wsum[wid] = v;
  __syncthreads();
  if (tid == 0) {
    int run = 0;
#pragma unroll
    for (int i = 0; i < 16; ++i) {
      int c = wsum[i];
      wsum[i] = run;
      run += c;
    }
    ((int*)(wsb + WS_COUNTS))[e] = run;
  }
  __syncthreads();
  int pos = wsum[wid] + v - cnt;  // exclusive prefix for this thread
  int* lists = (int*)(wsb + WS_LISTS) + e * T_TOK;
  int* posm = (int*)(wsb + WS_POS);
#pragma unroll
  for (int j = 0; j < 8; ++j) {
    const int t = t0 + j;
    int p = -1;
    if (flags & (1u << j)) {
      p = pos++;
      lists[p] = t;
    }
    posm[t * E_NUM + e] = p;
  }
}

// Tiled transpose+convert: src f32 [E][R][Cin] -> dst bf16 [E][Cin][R]
__global__ void transpose_kernel(const float* __restrict__ src, unsigned short* __restrict__ dst,
                                 int R, int Cin) {
  const int e = blockIdx.z;
  const int rt = blockIdx.y * 64, ct = blockIdx.x * 64;
  const float* se = src + (size_t)e * R * Cin;
  unsigned short* de = dst + (size_t)e * R * Cin;
  __shared__ unsigned short tile[64][68];
  const int tid = threadIdx.x;
  const int tr = tid >> 4, tc = (tid & 15) * 4;
#pragma unroll
  for (int it = 0; it < 4; ++it) {
    const int r = tr + it * 16;
    const float4 v = *(const float4*)(se + (size_t)(rt + r) * Cin + ct + tc);
    tile[tc + 0][r] = f2bf(v.x);
    tile[tc + 1][r] = f2bf(v.y);
    tile[tc + 2][r] = f2bf(v.z);
    tile[tc + 3][r] = f2bf(v.w);
  }
  __syncthreads();
#pragma unroll
  for (int it = 0; it < 4; ++it) {
    const int c = tr + it * 16;
    ushort4 o = *(const ushort4*)&tile[c][tc];
    *(ushort4*)(de + (size_t)(ct + c) * R + rt + tc) = o;
  }
}

// Fast grouped expert GEMM: weights pre-transposed bf16 in ws, no weight staging.
// Output: atomicAdd partials into compact[e][pos][c].
__global__ __launch_bounds__(512) void gemm_fast_kernel(const char* __restrict__ wsb,
                                                        float* __restrict__ compact) {
  const int e = blockIdx.x;
  const int ne = min(((const int*)(wsb + WS_COUNTS))[e], CAP);
  const int m0 = blockIdx.y * BT;
  if (m0 >= ne) return;
  const int mcnt = min(BT, ne - m0);
  const int i0 = blockIdx.z * IRANGE;

  const int* lists = (const int*)(wsb + WS_LISTS);
  const unsigned short* xb = (const unsigned short*)(wsb + WS_XB);
  const unsigned short* w1t = (const unsigned short*)(wsb + WS_W1T) + (size_t)e * I_DIM * C_DIM;
  const unsigned short* w2t = (const unsigned short*)(wsb + WS_W2T) + (size_t)e * C_DIM * I_DIM;

  __shared__ int tl[BT];
  __shared__ unsigned short s_h[BT][BI + 8];

  const int tid = threadIdx.x;
  if (tid < BT) tl[tid] = lists[e * T_TOK + min(m0 + tid, ne - 1)];
  __syncthreads();

  const int wv = tid >> 6, lane = tid & 63, g = lane >> 4, l15 = lane & 15;
  const int nt1 = wv & 1, mg = wv >> 1;

  const f32x4 zero4 = {0.f, 0.f, 0.f, 0.f};
  f32x4 acc[8][4];
#pragma unroll
  for (int m = 0; m < 8; ++m)
#pragma unroll
    for (int n = 0; n < 4; ++n) acc[m][n] = zero4;

  // stage-1 A rows are fixed across chunks
  const unsigned short* a0p = xb + (size_t)tl[mg * 32 + l15] * C_DIM;
  const unsigned short* a1p = xb + (size_t)tl[mg * 32 + 16 + l15] * C_DIM;

  for (int ci = 0; ci < NCHUNK; ++ci) {
    const int ib = i0 + ci * BI;
    // stage 1: H[128][32] = X @ W1c (B-rows direct from W1T global)
    f32x4 h0 = zero4, h1 = zero4;
    const unsigned short* brow = w1t + (size_t)(ib + nt1 * 16 + l15) * C_DIM;
#pragma unroll
    for (int kk = 0; kk < 16; ++kk) {
      const int k0 = kk * 32 + g * 8;
      const bf16x8 b = ldb8(brow + k0);
      h0 = __builtin_amdgcn_mfma_f32_16x16x32_bf16(ldb8(a0p + k0), b, h0, 0, 0, 0);
      h1 = __builtin_amdgcn_mfma_f32_16x16x32_bf16(ldb8(a1p + k0), b, h1, 0, 0, 0);
    }
    __syncthreads();  // previous chunk's stage-2 reads of s_h complete
    {
      const int col = nt1 * 16 + l15;
      const int rb = mg * 32 + g * 4;
#pragma unroll
      for (int r = 0; r < 4; ++r) {
        s_h[rb + r][col] = f2bf(gelu_f(h0[r]));
        s_h[rb + 16 + r][col] = f2bf(gelu_f(h1[r]));
      }
    }
    __syncthreads();
    // stage 2: acc += H @ W2c (wave owns C-columns [wv*64, wv*64+64))
    bf16x8 b2[4];
#pragma unroll
    for (int nt = 0; nt < 4; ++nt)
      b2[nt] = ldb8(w2t + (size_t)(wv * 64 + nt * 16 + l15) * I_DIM + ib + g * 8);
#pragma unroll
    for (int m = 0; m < 8; ++m) {
      const bf16x8 a2 = ldb8(&s_h[m * 16 + l15][g * 8]);
#pragma unroll
      for (int nt = 0; nt < 4; ++nt)
        acc[m][nt] = __builtin_amdgcn_mfma_f32_16x16x32_bf16(a2, b2[nt], acc[m][nt], 0, 0, 0);
    }
  }

  // epilogue: atomic add partials into compact[e][pos][c]
#pragma unroll
  for (int m = 0; m < 8; ++m) {
#pragma unroll
    for (int r = 0; r < 4; ++r) {
      const int row = m * 16 + g * 4 + r;
      if (row < mcnt) {
        float* dst = compact + ((size_t)e * CAP + m0 + row) * C_DIM + wv * 64 + l15;
#pragma unroll
        for (int nt = 0; nt < 4; ++nt) atomicAdd(dst + nt * 16, acc[m][nt][r]);
      }
    }
  }
}

// One pass: write full (value or 0 everywhere) + final = sum_e rw * full
__global__ void scatter_kernel(const float* __restrict__ compact, const char* __restrict__ wsb,
                               float* __restrict__ out) {
  const int t = blockIdx.x;
  const int tid = threadIdx.x;  // 256
  __shared__ float rws[E_NUM];
  __shared__ int ps[E_NUM];
  if (tid < E_NUM) {
    rws[tid] = ((const float*)(wsb + WS_RW))[t * E_NUM + tid];
    ps[tid] = ((const int*)(wsb + WS_POS))[t * E_NUM + tid];
  }
  __syncthreads();
  float a0 = 0.f, a1 = 0.f;
  float* full = out + OUT_FULL + (size_t)t * E_NUM * C_DIM;
#pragma unroll 1
  for (int e = 0; e < E_NUM; ++e) {
    const int p = ps[e];
    float v0 = 0.f, v1 = 0.f;
    if (p >= 0 && p < CAP) {
      const float* src = compact + ((size_t)e * CAP + p) * C_DIM;
      v0 = src[tid];
      v1 = src[tid + 256];
      const float w = rws[e];
      a0 += w * v0;
      a1 += w * v1;
    }
    full[e * C_DIM + tid] = v0;
    full[e * C_DIM + tid + 256] = v1;
  }
  out[(size_t)t * C_DIM + tid] = a0;
  out[(size_t)t * C_DIM + tid + 256] = a1;
}

// ---------------- fallback path (round-1 structure), used if ws too small ----------------
__global__ __launch_bounds__(512, 2) void gemm_kernel(
    const float* __restrict__ w1, const float* __restrict__ w2,
    const char* __restrict__ wsb, float* __restrict__ full) {
  const int e = blockIdx.x;
  const int ne = ((const int*)(wsb + WS_COUNTS))[e];
  const int m0 = blockIdx.y * BT;
  if (m0 >= ne) return;
  const int mcnt = min(BT, ne - m0);
  const int i0 = blockIdx.z * IRANGE;

  const int* lists = (const int*)(wsb + WS_LISTS);
  const unsigned short* xb = (const unsigned short*)(wsb + WS_XB);

  __shared__ int tl[BT];
  __shared__ unsigned short s_w1[2][C_DIM][18];
  __shared__ unsigned short s_h[BT][40];

  const int tid = threadIdx.x;
  if (tid < BT) tl[tid] = lists[e * T_TOK + min(m0 + tid, ne - 1)];

  const int wv = tid >> 6;
  const int lane = tid & 63;
  const int g = lane >> 4;
  const int l15 = lane & 15;
  const int nt1 = wv & 1;
  const int mg = wv >> 1;

  const f32x4 zero4 = {0.f, 0.f, 0.f, 0.f};
  f32x4 acc[8][4];
#pragma unroll
  for (int m = 0; m < 8; ++m)
#pragma unroll
    for (int n = 0; n < 4; ++n) acc[m][n] = zero4;

  const float* w1p = w1 + (size_t)e * C_DIM * I_DIM + i0;
  const float* w2p = w2 + (size_t)e * I_DIM * C_DIM + (size_t)i0 * C_DIM;

  for (int ci = 0; ci < NCHUNK; ++ci) {
#pragma unroll
    for (int it = 0; it < 8; ++it) {
      const int q = tid + it * 512;
      const int k = q >> 3;
      const int n4 = (q & 7) * 4;
      const float4 v = *(const float4*)(w1p + (size_t)k * I_DIM + ci * BI + n4);
      const int nt = n4 >> 4, nn = n4 & 15;
      s_w1[nt][k][nn + 0] = f2bf(v.x);
      s_w1[nt][k][nn + 1] = f2bf(v.y);
      s_w1[nt][k][nn + 2] = f2bf(v.z);
      s_w1[nt][k][nn + 3] = f2bf(v.w);
    }
    __syncthreads();
    {
      f32x4 hacc[2];
      hacc[0] = zero4;
      hacc[1] = zero4;
      for (int kk = 0; kk < 16; ++kk) {
        const int k0 = kk * 32;
        bf16x8 b;
#pragma unroll
        for (int j = 0; j < 8; ++j) b[j] = (short)s_w1[nt1][k0 + g * 8 + j][l15];
#pragma unroll
        for (int mf = 0; mf < 2; ++mf) {
          const int row = mg * 32 + mf * 16 + l15;
          const int t = tl[row];
          union { uint4 u; bf16x8 v; } av;
          av.u = *(const uint4*)(xb + (size_t)t * C_DIM + k0 + g * 8);
          hacc[mf] = __builtin_amdgcn_mfma_f32_16x16x32_bf16(av.v, b, hacc[mf], 0, 0, 0);
        }
      }
#pragma unroll
      for (int mf = 0; mf < 2; ++mf) {
        const int rbase = mg * 32 + mf * 16 + g * 4;
        const int col = nt1 * 16 + l15;
#pragma unroll
        for (int r = 0; r < 4; ++r) s_h[rbase + r][col] = f2bf(gelu_f(hacc[mf][r]));
      }
    }
    __syncthreads();
    {
      bf16x8 a2[8];
#pragma unroll
      for (int m = 0; m < 8; ++m) {
        union { uint4 u; bf16x8 v; } av;
        av.u = *(const uint4*)(&s_h[m * 16 + l15][g * 8]);
        a2[m] = av.v;
      }
#pragma unroll
      for (int nt = 0; nt < 4; ++nt) {
        const int c = wv * 64 + nt * 16 + l15;
        bf16x8 b;
#pragma unroll
        for (int j = 0; j < 8; ++j) {
          const int ki = ci * BI + g * 8 + j;
          b[j] = (short)f2bf(w2p[(size_t)ki * C_DIM + c]);
        }
#pragma unroll
        for (int m = 0; m < 8; ++m)
          acc[m][nt] = __builtin_amdgcn_mfma_f32_16x16x32_bf16(a2[m], b, acc[m][nt], 0, 0, 0);
      }
    }
    __syncthreads();
  }

#pragma unroll
  for (int m = 0; m < 8; ++m) {
#pragma unroll
    for (int r = 0; r < 4; ++r) {
      const int row = m * 16 + g * 4 + r;
      if (row < mcnt) {
        const int t = tl[row];
        float* dst = full + ((size_t)t * E_NUM + e) * C_DIM + wv * 64 + l15;
#pragma unroll
        for (int nt = 0; nt < 4; ++nt) atomicAdd(dst + nt * 16, acc[m][nt][r]);
      }
    }
  }
}

__global__ void finalize_kernel(const float* __restrict__ full, const char* __restrict__ wsb,
                                float* __restrict__ fin) {
  const int t = blockIdx.x;
  const int tid = threadIdx.x;
  const float* rw = (const float*)(wsb + WS_RW);
  __shared__ float rws[E_NUM];
  if (tid < E_NUM) rws[tid] = rw[t * E_NUM + tid];
  __syncthreads();
  float a0 = 0.f, a1 = 0.f;
  const float* base = full + (size_t)t * E_NUM * C_DIM;
#pragma unroll 1
  for (int e = 0; e < E_NUM; ++e) {
    const float w = rws[e];
    if (w != 0.0f) {
      a0 += w * base[e * C_DIM + tid];
      a1 += w * base[e * C_DIM + 256 + tid];
    }
  }
  fin[(size_t)t * C_DIM + tid] = a0;
  fin[(size_t)t * C_DIM + 256 + tid] = a1;
}

extern "C" void kernel_launch(void* const* d_in, const int* in_sizes, int n_in,
                              void* d_out, int out_size, void* d_ws, size_t ws_size,
                              hipStream_t stream) {
  const float* x = (const float*)d_in[0];
  const float* sim = (const float*)d_in[1];
  const float* gates = (const float*)d_in[2];
  const float* w1 = (const float*)d_in[3];
  const float* w2 = (const float*)d_in[4];
  float* out = (float*)d_out;
  char* wsb = (char*)d_ws;
  const int fast = ws_size >= (size_t)WS_NEED_FAST;

  hipLaunchKernelGGL(prep_kernel, dim3(1), dim3(64), 0, stream, sim, gates, wsb);
  hipLaunchKernelGGL(router_kernel, dim3(T_TOK / 4), dim3(256), 0, stream, x, sim, wsb, out);
  hipLaunchKernelGGL(build_lists_kernel, dim3(E_NUM), dim3(1024), 0, stream, wsb);

  if (fast) {
    // W1 [E][512][2048] -> W1T [E][2048][512]; W2 [E][2048][512] -> W2T [E][512][2048]
    hipLaunchKernelGGL(transpose_kernel, dim3(I_DIM / 64, C_DIM / 64, E_NUM), dim3(256), 0, stream,
                       w1, (unsigned short*)(wsb + WS_W1T), C_DIM, I_DIM);
    hipLaunchKernelGGL(transpose_kernel, dim3(C_DIM / 64, I_DIM / 64, E_NUM), dim3(256), 0, stream,
                       w2, (unsigned short*)(wsb + WS_W2T), I_DIM, C_DIM);
    hipMemsetAsync(wsb + WS_COMPACT, 0, (size_t)E_NUM * CAP * C_DIM * 4, stream);
    hipLaunchKernelGGL(gemm_fast_kernel, dim3(E_NUM, NTILE, ISPLIT), dim3(512), 0, stream,
                       wsb, (float*)(wsb + WS_COMPACT));
    hipLaunchKernelGGL(scatter_kernel, dim3(T_TOK), dim3(256), 0, stream,
                       (const float*)(wsb + WS_COMPACT), wsb, out);
  } else {
    hipMemsetAsync(d_out, 0, (size_t)out_size * sizeof(float), stream);
    hipLaunchKernelGGL(gemm_kernel, dim3(E_NUM, T_TOK / BT, ISPLIT), dim3(512), 0, stream,
                       w1, w2, wsb, out + OUT_FULL);
    hipLaunchKernelGGL(finalize_kernel, dim3(T_TOK), dim3(256), 0, stream, out + OUT_FULL, wsb, out);
  }
}